// Round 1
// baseline (282.784 us; speedup 1.0000x reference)
//
#include <hip/hip_runtime.h>
#include <stdint.h>
#include <math.h>

#define N_PTS 8192
#define K_SEL 32
#define LPR   16                 // lanes per row
#define RPB   16                 // rows per block (256 threads)
#define SLICE (N_PTS / LPR)      // 512 j's per lane
#define NBLK_MAIN (N_PTS / RPB)  // 512 blocks

// ---------------- threefry2x32 (JAX partitionable random_bits) ----------------
__device__ __forceinline__ uint32_t rotl32(uint32_t x, int r) {
  return (x << r) | (x >> (32 - r));
}

// bits for flat element idx of jax.random.normal(jax.random.key(42), ...):
// counter = (hi=0, lo=idx), key = (0, 42), output = x0 ^ x1.
__device__ __forceinline__ uint32_t threefry_bits(uint32_t idx) {
  const uint32_t k0 = 0u, k1 = 42u;
  const uint32_t k2c = k0 ^ k1 ^ 0x1BD11BDAu;
  uint32_t x0 = 0u, x1 = idx;
  x0 += k0; x1 += k1;
  x0 += x1; x1 = rotl32(x1, 13); x1 ^= x0;
  x0 += x1; x1 = rotl32(x1, 15); x1 ^= x0;
  x0 += x1; x1 = rotl32(x1, 26); x1 ^= x0;
  x0 += x1; x1 = rotl32(x1,  6); x1 ^= x0;
  x0 += k1; x1 += k2c + 1u;
  x0 += x1; x1 = rotl32(x1, 17); x1 ^= x0;
  x0 += x1; x1 = rotl32(x1, 29); x1 ^= x0;
  x0 += x1; x1 = rotl32(x1, 16); x1 ^= x0;
  x0 += x1; x1 = rotl32(x1, 24); x1 ^= x0;
  x0 += k2c; x1 += k0 + 2u;
  x0 += x1; x1 = rotl32(x1, 13); x1 ^= x0;
  x0 += x1; x1 = rotl32(x1, 15); x1 ^= x0;
  x0 += x1; x1 = rotl32(x1, 26); x1 ^= x0;
  x0 += x1; x1 = rotl32(x1,  6); x1 ^= x0;
  x0 += k0; x1 += k1 + 3u;
  x0 += x1; x1 = rotl32(x1, 17); x1 ^= x0;
  x0 += x1; x1 = rotl32(x1, 29); x1 ^= x0;
  x0 += x1; x1 = rotl32(x1, 16); x1 ^= x0;
  x0 += x1; x1 = rotl32(x1, 24); x1 ^= x0;
  x0 += k1; x1 += k2c + 4u;
  x0 += x1; x1 = rotl32(x1, 13); x1 ^= x0;
  x0 += x1; x1 = rotl32(x1, 15); x1 ^= x0;
  x0 += x1; x1 = rotl32(x1, 26); x1 ^= x0;
  x0 += x1; x1 = rotl32(x1,  6); x1 ^= x0;
  x0 += k2c; x1 += k0 + 5u;
  return x0 ^ x1;
}

// XLA ErfInv32 polynomial (Giles), matches lax.erf_inv on f32
__device__ __forceinline__ float erfinv_xla(float x) {
  float w = -log1pf(-x * x);
  float p;
  if (w < 5.0f) {
    w -= 2.5f;
    p = 2.81022636e-08f;
    p = fmaf(p, w, 3.43273939e-07f);
    p = fmaf(p, w, -3.5233877e-06f);
    p = fmaf(p, w, -4.39150654e-06f);
    p = fmaf(p, w, 0.00021858087f);
    p = fmaf(p, w, -0.00125372503f);
    p = fmaf(p, w, -0.00417768164f);
    p = fmaf(p, w, 0.246640727f);
    p = fmaf(p, w, 1.50140941f);
  } else {
    w = sqrtf(w) - 3.0f;
    p = -0.000200214257f;
    p = fmaf(p, w, 0.000100950558f);
    p = fmaf(p, w, 0.00134934322f);
    p = fmaf(p, w, -0.00367342844f);
    p = fmaf(p, w, 0.00573950773f);
    p = fmaf(p, w, -0.0076224613f);
    p = fmaf(p, w, 0.00943887047f);
    p = fmaf(p, w, 1.00167406f);
    p = fmaf(p, w, 2.83297682f);
  }
  return p * x;
}

__device__ __forceinline__ float jax_noise(uint32_t idx) {
  uint32_t bits = threefry_bits(idx);
  float uf = __uint_as_float((bits >> 9) | 0x3F800000u) - 1.0f;  // [0,1)
  const float lo_u = -0.99999994f;                               // nextafter(-1,0)
  float u = fmaxf(lo_u, fmaf(uf, 2.0f, lo_u));                   // (hi-lo) rounds to 2.0f
  return 1.4142135623730951f * erfinv_xla(u) * 0.01f;
}

// ---------------- kernel A: column mean/std (ddof=1), f64 deterministic ----------------
__global__ __launch_bounds__(256) void stats_kernel(const float* __restrict__ x,
                                                    float* __restrict__ stats) {
  __shared__ double red[256][4];
  int t = threadIdx.x;
  double s0 = 0, s1 = 0, q0 = 0, q1 = 0;
  const float4* x4 = (const float4*)x;
  for (int k = t; k < N_PTS / 2; k += 256) {
    float4 v = x4[k];  // point 2k: (x,y), point 2k+1: (z,w)
    s0 += (double)v.x + (double)v.z;
    s1 += (double)v.y + (double)v.w;
    q0 += (double)v.x * v.x + (double)v.z * v.z;
    q1 += (double)v.y * v.y + (double)v.w * v.w;
  }
  red[t][0] = s0; red[t][1] = s1; red[t][2] = q0; red[t][3] = q1;
  __syncthreads();
  for (int st = 128; st > 0; st >>= 1) {
    if (t < st) {
      red[t][0] += red[t + st][0]; red[t][1] += red[t + st][1];
      red[t][2] += red[t + st][2]; red[t][3] += red[t + st][3];
    }
    __syncthreads();
  }
  if (t == 0) {
    double n = (double)N_PTS;
    double m0 = red[0][0] / n, m1 = red[0][1] / n;
    double v0 = (red[0][2] - n * m0 * m0) / (n - 1.0);
    double v1 = (red[0][3] - n * m1 * m1) / (n - 1.0);
    stats[0] = (float)m0; stats[1] = (float)m1;
    stats[2] = (float)sqrt(v0); stats[3] = (float)sqrt(v1);
  }
}

// ---------------- kernel B: sigma + drift + noised h, per-block col partials ----------------
__global__ __launch_bounds__(256) void main_kernel(const float* __restrict__ x,
                                                   const float* __restrict__ stats,
                                                   float* __restrict__ h_out,
                                                   double* __restrict__ partials) {
  __shared__ float2 xs[N_PTS];  // 64KB: whole centered point set
  int t = threadIdx.x;
  const float mean0 = stats[0], mean1 = stats[1];

  // stage xc into LDS (coalesced float4 global, b128 LDS writes)
  const float4* x4 = (const float4*)x;
  for (int k = t; k < N_PTS / 2; k += 256) {
    float4 v = x4[k];
    ((float4*)xs)[k] = make_float4(v.x - mean0, v.y - mean1, v.z - mean0, v.w - mean1);
  }
  __syncthreads();

  const int rloc = t >> 4;         // 0..15 local row
  const int s    = t & 15;         // 0..15 lane-in-row
  const int row  = blockIdx.x * RPB + rloc;
  const float2 xi = xs[row];
  const float xi0 = xi.x, xi1 = xi.y;

  // ---- phase A: per-lane sorted top-32 of squared distances over strided slice ----
  float r[K_SEL];
#pragma unroll
  for (int k = 0; k < K_SEL; ++k) r[k] = 3.402823466e+38f;

  for (int tt = 0; tt < SLICE; ++tt) {
    float2 xj = xs[tt * LPR + s];  // 16 distinct addrs/wave, 4-way broadcast: conflict-free
    float dx = xi0 - xj.x;
    float dy = xi1 - xj.y;
    float d2 = fmaf(dx, dx, dy * dy);
    if (d2 < r[K_SEL - 1]) {
      // branchless sorted insert: new r[k] = min(max(r[k-1], v), r[k])
#pragma unroll
      for (int k = K_SEL - 1; k > 0; --k) r[k] = fminf(fmaxf(r[k - 1], d2), r[k]);
      r[0] = fminf(r[0], d2);
    }
  }

  // ---- exact rank-32 over union of 16 sorted lists: binary search on f32 bit ints ----
  uint32_t rb[K_SEL];
#pragma unroll
  for (int k = 0; k < K_SEL; ++k) rb[k] = __float_as_uint(r[k]);

  uint32_t blo = 0u, bhi = 0x7F800001u;  // smallest T with count(bits < T) >= 32
  for (int it = 0; it < 31; ++it) {
    uint32_t mid = (blo + bhi) >> 1;
    int c = 0;
#pragma unroll
    for (int k = 0; k < K_SEL; ++k) c += (rb[k] < mid) ? 1 : 0;
#pragma unroll
    for (int m = 1; m < LPR; m <<= 1) c += __shfl_xor(c, m, LPR);
    bool ge = (c >= K_SEL);
    bhi = ge ? mid : bhi;
    blo = ge ? blo : mid;
  }
  float d2_k  = __uint_as_float(bhi - 1u);  // exact 32nd-smallest squared distance
  float sigma = sqrtf(d2_k);
  float den   = fmaf(2.0f, sigma * sigma, 1e-8f);  // 2*sigma^2 + eps
  float k2    = -1.4426950408889634f / den;        // exp(-d/den) = exp2(d*k2)

  // ---- phase B: weight sums ----
  float sw = 0.f, swx = 0.f, swy = 0.f;
  for (int tt = 0; tt < SLICE; ++tt) {
    float2 xj = xs[tt * LPR + s];
    float dx = xi0 - xj.x;
    float dy = xi1 - xj.y;
    float d2 = fmaf(dx, dx, dy * dy);
    float d  = sqrtf(d2);
    float w  = exp2f(d * k2);
    sw += w;
    swx = fmaf(w, xj.x, swx);
    swy = fmaf(w, xj.y, swy);
  }
#pragma unroll
  for (int m = 1; m < LPR; m <<= 1) {
    sw  += __shfl_xor(sw,  m, LPR);
    swx += __shfl_xor(swx, m, LPR);
    swy += __shfl_xor(swy, m, LPR);
  }

  // all xs reads done; reuse LDS front for per-row h values
  __syncthreads();
  float* hrow = (float*)xs;  // [RPB][2]

  if (s < 2) {
    float inv   = 1.0f / (sw + 1e-8f);
    float drift = (s == 0 ? swx : swy) * inv;
    float xcv   = (s == 0 ? xi0 : xi1);
    uint32_t idx = (uint32_t)(2 * row + s);
    float h = xcv + 0.5f * (drift - xcv) + jax_noise(idx);  // step = D^-alpha = 0.5
    h_out[idx] = h;
    hrow[rloc * 2 + s] = h;
  }
  __syncthreads();
  if (t < 2) {  // deterministic per-block column partial sums (f64)
    double sm = 0.0, sq = 0.0;
    for (int k = 0; k < RPB; ++k) {
      double v = (double)hrow[k * 2 + t];
      sm += v; sq += v * v;
    }
    partials[blockIdx.x * 4 + t]     = sm;
    partials[blockIdx.x * 4 + 2 + t] = sq;
  }
}

// ---------------- kernel C: reduce partials -> scale = std/(cur_std+eps) ----------------
__global__ __launch_bounds__(64) void scale_kernel(const double* __restrict__ partials,
                                                   const float* __restrict__ stats,
                                                   float* __restrict__ scale) {
  __shared__ double red[64][4];
  int t = threadIdx.x;
  double a0 = 0, a1 = 0, a2 = 0, a3 = 0;
  for (int b = t; b < NBLK_MAIN; b += 64) {
    a0 += partials[b * 4 + 0]; a1 += partials[b * 4 + 1];
    a2 += partials[b * 4 + 2]; a3 += partials[b * 4 + 3];
  }
  red[t][0] = a0; red[t][1] = a1; red[t][2] = a2; red[t][3] = a3;
  __syncthreads();
  if (t == 0) {
    double s0 = 0, s1 = 0, q0 = 0, q1 = 0;
    for (int k = 0; k < 64; ++k) {
      s0 += red[k][0]; s1 += red[k][1]; q0 += red[k][2]; q1 += red[k][3];
    }
    double n = (double)N_PTS;
    double m0 = s0 / n, m1 = s1 / n;
    double v0 = (q0 - n * m0 * m0) / (n - 1.0);
    double v1 = (q1 - n * m1 * m1) / (n - 1.0);
    scale[0] = stats[2] / ((float)sqrt(v0) + 1e-8f);
    scale[1] = stats[3] / ((float)sqrt(v1) + 1e-8f);
  }
}

// ---------------- kernel D: out = h*scale + mean (in place on d_out) ----------------
__global__ __launch_bounds__(256) void final_kernel(float* __restrict__ h,
                                                    const float* __restrict__ stats,
                                                    const float* __restrict__ scale) {
  int i = blockIdx.x * 256 + threadIdx.x;
  int d = i & 1;
  h[i] = fmaf(h[i], scale[d], stats[d]);
}

extern "C" void kernel_launch(void* const* d_in, const int* in_sizes, int n_in,
                              void* d_out, int out_size, void* d_ws, size_t ws_size,
                              hipStream_t stream) {
  const float* x = (const float*)d_in[0];
  float* out = (float*)d_out;
  float* stats = (float*)d_ws;                         // 4 f32
  float* scale = stats + 4;                            // 2 f32
  double* partials = (double*)((char*)d_ws + 64);      // 512*4 f64 = 16KB

  stats_kernel<<<1, 256, 0, stream>>>(x, stats);
  main_kernel<<<NBLK_MAIN, 256, 0, stream>>>(x, stats, out, partials);
  scale_kernel<<<1, 64, 0, stream>>>(partials, stats, scale);
  final_kernel<<<16384 / 256, 256, 0, stream>>>(out, stats, scale);
}

// Round 2
// 79.575 us; speedup vs baseline: 3.5537x; 3.5537x over previous
//
#include <hip/hip_runtime.h>
#include <stdint.h>
#include <math.h>

#define N_PTS 8192
#define K_LANE 8                  // per-lane top-K (64 lanes/row -> provably enough for rank-32)
#define RPB 4                     // rows (waves) per block of 256 threads
#define NBLK_MAIN (N_PTS / RPB)   // 2048
#define CHUNK 4096                // points per LDS chunk (32 KB)
#define CF4 (CHUNK / 2)           // float4 per chunk = 2048
#define ITERS (CF4 / 64)          // float4 iters per lane per chunk = 32

// ---------------- threefry2x32 (JAX partitionable random_bits) ----------------
__device__ __forceinline__ uint32_t rotl32(uint32_t x, int r) {
  return (x << r) | (x >> (32 - r));
}

__device__ __forceinline__ uint32_t threefry_bits(uint32_t idx) {
  const uint32_t k0 = 0u, k1 = 42u;
  const uint32_t k2c = k0 ^ k1 ^ 0x1BD11BDAu;
  uint32_t x0 = 0u, x1 = idx;
  x0 += k0; x1 += k1;
  x0 += x1; x1 = rotl32(x1, 13); x1 ^= x0;
  x0 += x1; x1 = rotl32(x1, 15); x1 ^= x0;
  x0 += x1; x1 = rotl32(x1, 26); x1 ^= x0;
  x0 += x1; x1 = rotl32(x1,  6); x1 ^= x0;
  x0 += k1; x1 += k2c + 1u;
  x0 += x1; x1 = rotl32(x1, 17); x1 ^= x0;
  x0 += x1; x1 = rotl32(x1, 29); x1 ^= x0;
  x0 += x1; x1 = rotl32(x1, 16); x1 ^= x0;
  x0 += x1; x1 = rotl32(x1, 24); x1 ^= x0;
  x0 += k2c; x1 += k0 + 2u;
  x0 += x1; x1 = rotl32(x1, 13); x1 ^= x0;
  x0 += x1; x1 = rotl32(x1, 15); x1 ^= x0;
  x0 += x1; x1 = rotl32(x1, 26); x1 ^= x0;
  x0 += x1; x1 = rotl32(x1,  6); x1 ^= x0;
  x0 += k0; x1 += k1 + 3u;
  x0 += x1; x1 = rotl32(x1, 17); x1 ^= x0;
  x0 += x1; x1 = rotl32(x1, 29); x1 ^= x0;
  x0 += x1; x1 = rotl32(x1, 16); x1 ^= x0;
  x0 += x1; x1 = rotl32(x1, 24); x1 ^= x0;
  x0 += k1; x1 += k2c + 4u;
  x0 += x1; x1 = rotl32(x1, 13); x1 ^= x0;
  x0 += x1; x1 = rotl32(x1, 15); x1 ^= x0;
  x0 += x1; x1 = rotl32(x1, 26); x1 ^= x0;
  x0 += x1; x1 = rotl32(x1,  6); x1 ^= x0;
  x0 += k2c; x1 += k0 + 5u;
  return x0 ^ x1;
}

// XLA ErfInv32 polynomial (Giles), matches lax.erf_inv on f32
__device__ __forceinline__ float erfinv_xla(float x) {
  float w = -log1pf(-x * x);
  float p;
  if (w < 5.0f) {
    w -= 2.5f;
    p = 2.81022636e-08f;
    p = fmaf(p, w, 3.43273939e-07f);
    p = fmaf(p, w, -3.5233877e-06f);
    p = fmaf(p, w, -4.39150654e-06f);
    p = fmaf(p, w, 0.00021858087f);
    p = fmaf(p, w, -0.00125372503f);
    p = fmaf(p, w, -0.00417768164f);
    p = fmaf(p, w, 0.246640727f);
    p = fmaf(p, w, 1.50140941f);
  } else {
    w = sqrtf(w) - 3.0f;
    p = -0.000200214257f;
    p = fmaf(p, w, 0.000100950558f);
    p = fmaf(p, w, 0.00134934322f);
    p = fmaf(p, w, -0.00367342844f);
    p = fmaf(p, w, 0.00573950773f);
    p = fmaf(p, w, -0.0076224613f);
    p = fmaf(p, w, 0.00943887047f);
    p = fmaf(p, w, 1.00167406f);
    p = fmaf(p, w, 2.83297682f);
  }
  return p * x;
}

__device__ __forceinline__ float jax_noise(uint32_t idx) {
  uint32_t bits = threefry_bits(idx);
  float uf = __uint_as_float((bits >> 9) | 0x3F800000u) - 1.0f;  // [0,1)
  const float lo_u = -0.99999994f;                               // nextafter(-1,0)
  float u = fmaxf(lo_u, fmaf(uf, 2.0f, lo_u));
  return 1.4142135623730951f * erfinv_xla(u) * 0.01f;
}

// branchless sorted top-8 insert (descending-k reads old values: no dep chain)
__device__ __forceinline__ void ins8(float (&r)[K_LANE], float v) {
#pragma unroll
  for (int k = K_LANE - 1; k > 0; --k) r[k] = fminf(fmaxf(r[k - 1], v), r[k]);
  r[0] = fminf(r[0], v);
}

// ---------------- kernel A: column mean/std (ddof=1), f64 deterministic ----------------
__global__ __launch_bounds__(256) void stats_kernel(const float* __restrict__ x,
                                                    float* __restrict__ stats) {
  __shared__ double red[256][4];
  int t = threadIdx.x;
  double s0 = 0, s1 = 0, q0 = 0, q1 = 0;
  const float4* x4 = (const float4*)x;
  for (int k = t; k < N_PTS / 2; k += 256) {
    float4 v = x4[k];
    s0 += (double)v.x + (double)v.z;
    s1 += (double)v.y + (double)v.w;
    q0 += (double)v.x * v.x + (double)v.z * v.z;
    q1 += (double)v.y * v.y + (double)v.w * v.w;
  }
  red[t][0] = s0; red[t][1] = s1; red[t][2] = q0; red[t][3] = q1;
  __syncthreads();
  for (int st = 128; st > 0; st >>= 1) {
    if (t < st) {
      red[t][0] += red[t + st][0]; red[t][1] += red[t + st][1];
      red[t][2] += red[t + st][2]; red[t][3] += red[t + st][3];
    }
    __syncthreads();
  }
  if (t == 0) {
    double n = (double)N_PTS;
    double m0 = red[0][0] / n, m1 = red[0][1] / n;
    double v0 = (red[0][2] - n * m0 * m0) / (n - 1.0);
    double v1 = (red[0][3] - n * m1 * m1) / (n - 1.0);
    stats[0] = (float)m0; stats[1] = (float)m1;
    stats[2] = (float)sqrt(v0); stats[3] = (float)sqrt(v1);
  }
}

// ---------------- kernel B: one row per wave; sigma + drift + noised h ----------------
__global__ __launch_bounds__(256, 4) void main_kernel(const float* __restrict__ x,
                                                      const float* __restrict__ stats,
                                                      float* __restrict__ h_out,
                                                      double* __restrict__ partials) {
  __shared__ float2 xs[CHUNK];  // 32 KB -> 4 blocks/CU (16 waves/CU)
  const int t = threadIdx.x;
  const int w = t >> 6;   // wave = local row 0..3
  const int s = t & 63;   // lane in wave
  const int row = blockIdx.x * RPB + w;
  const float mean0 = stats[0], mean1 = stats[1];

  // own point from global (uniform across wave -> broadcast load)
  const float2 xg = ((const float2*)x)[row];
  const float xi0 = xg.x - mean0, xi1 = xg.y - mean1;

  const float4* x4 = (const float4*)x;
  float4* xs4 = (float4*)xs;

  auto STAGE = [&](int c) {  // stage chunk c (centered) into LDS
#pragma unroll
    for (int k = 0; k < CF4 / 256; ++k) {  // 8 float4 per thread
      float4 v = x4[c * CF4 + k * 256 + t];
      xs4[k * 256 + t] = make_float4(v.x - mean0, v.y - mean1, v.z - mean0, v.w - mean1);
    }
  };

  // ---- phase A state: per-lane sorted top-8 of squared distances ----
  float r[K_LANE];
#pragma unroll
  for (int k = 0; k < K_LANE; ++k) r[k] = 3.402823466e+38f;

  auto PHA = [&]() {
#pragma unroll 4
    for (int tt = 0; tt < ITERS; ++tt) {
      float4 p = xs4[tt * 64 + s];  // 2 points
      float dx0 = xi0 - p.x, dy0 = xi1 - p.y;
      float dx1 = xi0 - p.z, dy1 = xi1 - p.w;
      float d20 = fmaf(dy0, dy0, dx0 * dx0);
      float d21 = fmaf(dy1, dy1, dx1 * dx1);
      ins8(r, d20);
      ins8(r, d21);
    }
  };

  float sw = 0.f, swx = 0.f, swy = 0.f;
  float k2;  // set after rank search

  auto PHB = [&]() {
#pragma unroll 4
    for (int tt = 0; tt < ITERS; ++tt) {
      float4 p = xs4[tt * 64 + s];
      float dx0 = xi0 - p.x, dy0 = xi1 - p.y;
      float dx1 = xi0 - p.z, dy1 = xi1 - p.w;
      float d20 = fmaf(dy0, dy0, dx0 * dx0);
      float d21 = fmaf(dy1, dy1, dx1 * dx1);
      float w0 = __builtin_amdgcn_exp2f(__builtin_amdgcn_sqrtf(d20) * k2);
      float w1 = __builtin_amdgcn_exp2f(__builtin_amdgcn_sqrtf(d21) * k2);
      sw += w0 + w1;
      swx = fmaf(w0, p.x, swx); swy = fmaf(w0, p.y, swy);
      swx = fmaf(w1, p.z, swx); swy = fmaf(w1, p.w, swy);
    }
  };

  STAGE(0); __syncthreads();
  PHA();    __syncthreads();
  STAGE(1); __syncthreads();
  PHA();    // chunk 1

  // ---- exact rank-32 over union of 64 sorted 8-lists: ballot + scalar popcount ----
  uint32_t rb[K_LANE];
#pragma unroll
  for (int k = 0; k < K_LANE; ++k) rb[k] = __float_as_uint(r[k]);
  uint32_t blo = 0u, bhi = 0x7F800001u;  // smallest T with count(bits < T) >= 32
  for (int it = 0; it < 31; ++it) {
    uint32_t mid = (blo + bhi) >> 1;
    int c = 0;
#pragma unroll
    for (int k = 0; k < K_LANE; ++k) c += __popcll(__ballot(rb[k] < mid));
    bool ge = (c >= 32);
    bhi = ge ? mid : bhi;
    blo = ge ? blo : mid;
  }
  float d2k = __uint_as_float(bhi - 1u);     // exact 32nd-smallest squared distance
  float den = fmaf(2.0f, d2k, 1e-8f);        // 2*sigma^2 + eps
  k2 = -1.4426950408889634f / den;           // exp(-d/den) = exp2(d*k2)

  PHB();    // chunk 1 still resident
  __syncthreads();
  STAGE(0); __syncthreads();
  PHB();    // chunk 0

  // ---- wave reduce (once) ----
#pragma unroll
  for (int m = 1; m < 64; m <<= 1) {
    sw  += __shfl_xor(sw,  m);
    swx += __shfl_xor(swx, m);
    swy += __shfl_xor(swy, m);
  }

  __syncthreads();              // all xs reads complete; reuse LDS front
  float* hrow = (float*)xs;     // [RPB][2]
  if (s < 2) {
    float inv   = 1.0f / (sw + 1e-8f);
    float drift = (s == 0 ? swx : swy) * inv;
    float xcv   = (s == 0 ? xi0 : xi1);
    uint32_t idx = 2u * (uint32_t)row + (uint32_t)s;
    float h = fmaf(0.5f, drift - xcv, xcv) + jax_noise(idx);  // step = D^-alpha = 0.5
    h_out[idx] = h;
    hrow[w * 2 + s] = h;
  }
  __syncthreads();
  if (t < 2) {  // deterministic per-block column partials (f64)
    double sm = 0.0, sq = 0.0;
    for (int k = 0; k < RPB; ++k) {
      double v = (double)hrow[k * 2 + t];
      sm += v; sq += v * v;
    }
    partials[blockIdx.x * 4 + t]     = sm;
    partials[blockIdx.x * 4 + 2 + t] = sq;
  }
}

// ---------------- kernel C: reduce partials -> scale = std/(cur_std+eps) ----------------
__global__ __launch_bounds__(64) void scale_kernel(const double* __restrict__ partials,
                                                   const float* __restrict__ stats,
                                                   float* __restrict__ scale) {
  __shared__ double red[64][4];
  int t = threadIdx.x;
  double a0 = 0, a1 = 0, a2 = 0, a3 = 0;
  for (int b = t; b < NBLK_MAIN; b += 64) {
    a0 += partials[b * 4 + 0]; a1 += partials[b * 4 + 1];
    a2 += partials[b * 4 + 2]; a3 += partials[b * 4 + 3];
  }
  red[t][0] = a0; red[t][1] = a1; red[t][2] = a2; red[t][3] = a3;
  __syncthreads();
  if (t == 0) {
    double s0 = 0, s1 = 0, q0 = 0, q1 = 0;
    for (int k = 0; k < 64; ++k) {
      s0 += red[k][0]; s1 += red[k][1]; q0 += red[k][2]; q1 += red[k][3];
    }
    double n = (double)N_PTS;
    double m0 = s0 / n, m1 = s1 / n;
    double v0 = (q0 - n * m0 * m0) / (n - 1.0);
    double v1 = (q1 - n * m1 * m1) / (n - 1.0);
    scale[0] = stats[2] / ((float)sqrt(v0) + 1e-8f);
    scale[1] = stats[3] / ((float)sqrt(v1) + 1e-8f);
  }
}

// ---------------- kernel D: out = h*scale + mean ----------------
__global__ __launch_bounds__(256) void final_kernel(float* __restrict__ h,
                                                    const float* __restrict__ stats,
                                                    const float* __restrict__ scale) {
  int i = blockIdx.x * 256 + threadIdx.x;
  int d = i & 1;
  h[i] = fmaf(h[i], scale[d], stats[d]);
}

extern "C" void kernel_launch(void* const* d_in, const int* in_sizes, int n_in,
                              void* d_out, int out_size, void* d_ws, size_t ws_size,
                              hipStream_t stream) {
  const float* x = (const float*)d_in[0];
  float* out = (float*)d_out;
  float* stats = (float*)d_ws;                      // 4 f32
  float* scale = stats + 4;                         // 2 f32
  double* partials = (double*)((char*)d_ws + 64);   // 2048*4 f64 = 64 KB

  stats_kernel<<<1, 256, 0, stream>>>(x, stats);
  main_kernel<<<NBLK_MAIN, 256, 0, stream>>>(x, stats, out, partials);
  scale_kernel<<<1, 64, 0, stream>>>(partials, stats, scale);
  final_kernel<<<16384 / 256, 256, 0, stream>>>(out, stats, scale);
}

// Round 4
// 72.522 us; speedup vs baseline: 3.8993x; 1.0973x over previous
//
#include <hip/hip_runtime.h>
#include <stdint.h>
#include <math.h>

#define N_PTS 8192
#define WPB   8                    // waves (rows) per block
#define TPB   (WPB * 64)           // 512 threads
#define NBLK  (N_PTS / WPB)        // 1024 blocks = 4/CU * 256 CU exactly
#define AITER (N_PTS / 64 / 4)     // 32 uint4 iterations per lane

typedef __fp16 h2 __attribute__((ext_vector_type(2)));
typedef uint32_t u32;
union H2U { u32 u; h2 h; };

// ---------------- threefry2x32 (JAX partitionable random_bits) ----------------
__device__ __forceinline__ uint32_t rotl32(uint32_t x, int r) {
  return (x << r) | (x >> (32 - r));
}

__device__ __forceinline__ uint32_t threefry_bits(uint32_t idx) {
  const uint32_t k0 = 0u, k1 = 42u;
  const uint32_t k2c = k0 ^ k1 ^ 0x1BD11BDAu;
  uint32_t x0 = 0u, x1 = idx;
  x0 += k0; x1 += k1;
  x0 += x1; x1 = rotl32(x1, 13); x1 ^= x0;
  x0 += x1; x1 = rotl32(x1, 15); x1 ^= x0;
  x0 += x1; x1 = rotl32(x1, 26); x1 ^= x0;
  x0 += x1; x1 = rotl32(x1,  6); x1 ^= x0;
  x0 += k1; x1 += k2c + 1u;
  x0 += x1; x1 = rotl32(x1, 17); x1 ^= x0;
  x0 += x1; x1 = rotl32(x1, 29); x1 ^= x0;
  x0 += x1; x1 = rotl32(x1, 16); x1 ^= x0;
  x0 += x1; x1 = rotl32(x1, 24); x1 ^= x0;
  x0 += k2c; x1 += k0 + 2u;
  x0 += x1; x1 = rotl32(x1, 13); x1 ^= x0;
  x0 += x1; x1 = rotl32(x1, 15); x1 ^= x0;
  x0 += x1; x1 = rotl32(x1, 26); x1 ^= x0;
  x0 += x1; x1 = rotl32(x1,  6); x1 ^= x0;
  x0 += k0; x1 += k1 + 3u;
  x0 += x1; x1 = rotl32(x1, 17); x1 ^= x0;
  x0 += x1; x1 = rotl32(x1, 29); x1 ^= x0;
  x0 += x1; x1 = rotl32(x1, 16); x1 ^= x0;
  x0 += x1; x1 = rotl32(x1, 24); x1 ^= x0;
  x0 += k1; x1 += k2c + 4u;
  x0 += x1; x1 = rotl32(x1, 13); x1 ^= x0;
  x0 += x1; x1 = rotl32(x1, 15); x1 ^= x0;
  x0 += x1; x1 = rotl32(x1, 26); x1 ^= x0;
  x0 += x1; x1 = rotl32(x1,  6); x1 ^= x0;
  x0 += k2c; x1 += k0 + 5u;
  return x0 ^ x1;
}

__device__ __forceinline__ float erfinv_xla(float x) {
  float w = -log1pf(-x * x);
  float p;
  if (w < 5.0f) {
    w -= 2.5f;
    p = 2.81022636e-08f;
    p = fmaf(p, w, 3.43273939e-07f);
    p = fmaf(p, w, -3.5233877e-06f);
    p = fmaf(p, w, -4.39150654e-06f);
    p = fmaf(p, w, 0.00021858087f);
    p = fmaf(p, w, -0.00125372503f);
    p = fmaf(p, w, -0.00417768164f);
    p = fmaf(p, w, 0.246640727f);
    p = fmaf(p, w, 1.50140941f);
  } else {
    w = sqrtf(w) - 3.0f;
    p = -0.000200214257f;
    p = fmaf(p, w, 0.000100950558f);
    p = fmaf(p, w, 0.00134934322f);
    p = fmaf(p, w, -0.00367342844f);
    p = fmaf(p, w, 0.00573950773f);
    p = fmaf(p, w, -0.0076224613f);
    p = fmaf(p, w, 0.00943887047f);
    p = fmaf(p, w, 1.00167406f);
    p = fmaf(p, w, 2.83297682f);
  }
  return p * x;
}

__device__ __forceinline__ float jax_noise(uint32_t idx) {
  uint32_t bits = threefry_bits(idx);
  float uf = __uint_as_float((bits >> 9) | 0x3F800000u) - 1.0f;
  const float lo_u = -0.99999994f;
  float u = fmaxf(lo_u, fmaf(uf, 2.0f, lo_u));
  return 1.4142135623730951f * erfinv_xla(u) * 0.01f;
}

// dx,dy packed -> f32 squared distance
__device__ __forceinline__ float dot2(h2 a) {
#if __has_builtin(__builtin_amdgcn_fdot2)
  return __builtin_amdgcn_fdot2(a, a, 0.0f, false);
#else
  float ax = (float)a.x, ay = (float)a.y;
  return fmaf(ax, ax, ay * ay);
#endif
}

// ---------------- kernel A: column mean/std (ddof=1), f64 deterministic ----------------
__global__ __launch_bounds__(256) void stats_kernel(const float* __restrict__ x,
                                                    float* __restrict__ stats) {
  __shared__ double red[256][4];
  int t = threadIdx.x;
  double s0 = 0, s1 = 0, q0 = 0, q1 = 0;
  const float4* x4 = (const float4*)x;
  for (int k = t; k < N_PTS / 2; k += 256) {
    float4 v = x4[k];
    s0 += (double)v.x + (double)v.z;
    s1 += (double)v.y + (double)v.w;
    q0 += (double)v.x * v.x + (double)v.z * v.z;
    q1 += (double)v.y * v.y + (double)v.w * v.w;
  }
  red[t][0] = s0; red[t][1] = s1; red[t][2] = q0; red[t][3] = q1;
  __syncthreads();
  for (int st = 128; st > 0; st >>= 1) {
    if (t < st) {
      red[t][0] += red[t + st][0]; red[t][1] += red[t + st][1];
      red[t][2] += red[t + st][2]; red[t][3] += red[t + st][3];
    }
    __syncthreads();
  }
  if (t == 0) {
    double n = (double)N_PTS;
    double m0 = red[0][0] / n, m1 = red[0][1] / n;
    double v0 = (red[0][2] - n * m0 * m0) / (n - 1.0);
    double v1 = (red[0][3] - n * m1 * m1) / (n - 1.0);
    stats[0] = (float)m0; stats[1] = (float)m1;
    stats[2] = (float)sqrt(v0); stats[3] = (float)sqrt(v1);
  }
}

// ---------------- kernel B: one row per wave, f16-packed point set ----------------
__global__ __launch_bounds__(TPB, 8) void main_kernel(const float* __restrict__ x,
                                                      const float* __restrict__ stats,
                                                      float* __restrict__ h_out,
                                                      double* __restrict__ partials) {
  __shared__ u32 xs[N_PTS];  // packed half2 centered points, 32 KB
  const int t = threadIdx.x;
  const int w = t >> 6;      // wave = local row 0..7
  const int s = t & 63;
  const int row = blockIdx.x * WPB + w;
  const float mean0 = stats[0], mean1 = stats[1];

  // own point (wave-uniform broadcast load); exact f32 for the update step
  const float2 xg = ((const float2*)x)[row];
  const float xi0 = xg.x - mean0, xi1 = xg.y - mean1;
  // f16 twin, bit-identical to the staged copy (guarantees self-distance == 0)
  const h2 xih = __builtin_amdgcn_cvt_pkrtz(xi0, xi1);

  // stage whole centered point set as packed f16
  const float4* x4 = (const float4*)x;
#pragma unroll 4
  for (int k = 0; k < N_PTS / 2 / TPB; ++k) {  // 8 iterations
    float4 v = x4[k * TPB + t];
    h2 a = __builtin_amdgcn_cvt_pkrtz(v.x - mean0, v.y - mean1);
    h2 b = __builtin_amdgcn_cvt_pkrtz(v.z - mean0, v.w - mean1);
    ((uint2*)xs)[k * TPB + t] =
        make_uint2(__builtin_bit_cast(u32, a), __builtin_bit_cast(u32, b));
  }
  __syncthreads();

  // ---- phase A: two packed top-8 lists per lane (128 sub-lists per row) ----
  h2 r[8];
  const h2 INF2 = __builtin_bit_cast(h2, 0x7C007C00u);
#pragma unroll
  for (int k = 0; k < 8; ++k) r[k] = INF2;

  const uint4* xsv = (const uint4*)xs;
#pragma unroll 4
  for (int tt = 0; tt < AITER; ++tt) {
    uint4 q = xsv[tt * 64 + s];  // 4 points
    H2U p0, p1, p2, p3;
    p0.u = q.x; p1.u = q.y; p2.u = q.z; p3.u = q.w;
    float d20 = dot2(xih - p0.h);
    float d21 = dot2(xih - p1.h);
    float d22 = dot2(xih - p2.h);
    float d23 = dot2(xih - p3.h);
    h2 e01 = __builtin_amdgcn_cvt_pkrtz(d20, d21);
    h2 e23 = __builtin_amdgcn_cvt_pkrtz(d22, d23);
    // packed sorted insert: maintains lo-list and hi-list simultaneously
#pragma unroll
    for (int k = 7; k > 0; --k)
      r[k] = __builtin_elementwise_min(__builtin_elementwise_max(r[k - 1], e01), r[k]);
    r[0] = __builtin_elementwise_min(r[0], e01);
#pragma unroll
    for (int k = 7; k > 0; --k)
      r[k] = __builtin_elementwise_min(__builtin_elementwise_max(r[k - 1], e23), r[k]);
    r[0] = __builtin_elementwise_min(r[0], e23);
  }

  // ---- exact rank-32 over 128 sorted sub-lists: binary search in u16-bit space ----
  u32 lo[8], hi[8];
#pragma unroll
  for (int k = 0; k < 8; ++k) {
    u32 b = __builtin_bit_cast(u32, r[k]);
    lo[k] = b & 0xFFFFu;
    hi[k] = b >> 16;
  }
  u32 blo = 0u, bhi = 0x7C01u;  // smallest T with count(bits < T) >= 32
  for (int it = 0; it < 15; ++it) {
    u32 mid = (blo + bhi) >> 1;
    int c = 0;
#pragma unroll
    for (int k = 0; k < 8; ++k) {
      c += __popcll(__ballot(lo[k] < mid));
      c += __popcll(__ballot(hi[k] < mid));
    }
    bool ge = (c >= 32);
    bhi = ge ? mid : bhi;
    blo = ge ? blo : mid;
  }
  unsigned short v32 = (unsigned short)(bhi - 1u);   // 32nd-smallest d^2 (f16 bits)
  float d2k = (float)__builtin_bit_cast(__fp16, v32); // sigma^2
  float den = fmaf(2.0f, d2k, 1e-8f);
  float k2 = -1.4426950408889634f / den;              // exp(-d/den) = exp2(d*k2)

  // ---- phase B: weight sums over the resident f16 point set ----
  float sw = 0.f, swx = 0.f, swy = 0.f;
#pragma unroll 4
  for (int tt = 0; tt < AITER; ++tt) {
    uint4 q = xsv[tt * 64 + s];
#pragma unroll
    for (int j = 0; j < 4; ++j) {
      H2U p;
      p.u = (j == 0) ? q.x : (j == 1) ? q.y : (j == 2) ? q.z : q.w;
      float d2 = dot2(xih - p.h);
      float d = __builtin_amdgcn_sqrtf(d2);
      float wgt = __builtin_amdgcn_exp2f(d * k2);
      sw += wgt;
      swx = fmaf(wgt, (float)p.h.x, swx);
      swy = fmaf(wgt, (float)p.h.y, swy);
    }
  }
#pragma unroll
  for (int m = 1; m < 64; m <<= 1) {
    sw  += __shfl_xor(sw,  m);
    swx += __shfl_xor(swx, m);
    swy += __shfl_xor(swy, m);
  }

  __syncthreads();           // all xs reads complete; reuse LDS front
  float* hrow = (float*)xs;  // [WPB][2]
  if (s < 2) {
    float inv   = 1.0f / (sw + 1e-8f);
    float drift = (s == 0 ? swx : swy) * inv;
    float xcv   = (s == 0 ? xi0 : xi1);
    uint32_t idx = 2u * (uint32_t)row + (uint32_t)s;
    float h = fmaf(0.5f, drift - xcv, xcv) + jax_noise(idx);  // step = D^-alpha = 0.5
    h_out[idx] = h;
    hrow[w * 2 + s] = h;
  }
  __syncthreads();
  if (t < 2) {  // deterministic per-block column partials (f64)
    double sm = 0.0, sq = 0.0;
#pragma unroll
    for (int k = 0; k < WPB; ++k) {
      double v = (double)hrow[k * 2 + t];
      sm += v; sq += v * v;
    }
    partials[blockIdx.x * 4 + t]     = sm;
    partials[blockIdx.x * 4 + 2 + t] = sq;
  }
}

// ---------------- kernel C: reduce partials -> scale = std/(cur_std+eps) ----------------
__global__ __launch_bounds__(64) void scale_kernel(const double* __restrict__ partials,
                                                   const float* __restrict__ stats,
                                                   float* __restrict__ scale) {
  __shared__ double red[64][4];
  int t = threadIdx.x;
  double a0 = 0, a1 = 0, a2 = 0, a3 = 0;
  for (int b = t; b < NBLK; b += 64) {
    a0 += partials[b * 4 + 0]; a1 += partials[b * 4 + 1];
    a2 += partials[b * 4 + 2]; a3 += partials[b * 4 + 3];
  }
  red[t][0] = a0; red[t][1] = a1; red[t][2] = a2; red[t][3] = a3;
  __syncthreads();
  if (t == 0) {
    double s0 = 0, s1 = 0, q0 = 0, q1 = 0;
    for (int k = 0; k < 64; ++k) {
      s0 += red[k][0]; s1 += red[k][1]; q0 += red[k][2]; q1 += red[k][3];
    }
    double n = (double)N_PTS;
    double m0 = s0 / n, m1 = s1 / n;
    double v0 = (q0 - n * m0 * m0) / (n - 1.0);
    double v1 = (q1 - n * m1 * m1) / (n - 1.0);
    scale[0] = stats[2] / ((float)sqrt(v0) + 1e-8f);
    scale[1] = stats[3] / ((float)sqrt(v1) + 1e-8f);
  }
}

// ---------------- kernel D: out = h*scale + mean ----------------
__global__ __launch_bounds__(256) void final_kernel(float* __restrict__ h,
                                                    const float* __restrict__ stats,
                                                    const float* __restrict__ scale) {
  int i = blockIdx.x * 256 + threadIdx.x;
  int d = i & 1;
  h[i] = fmaf(h[i], scale[d], stats[d]);
}

extern "C" void kernel_launch(void* const* d_in, const int* in_sizes, int n_in,
                              void* d_out, int out_size, void* d_ws, size_t ws_size,
                              hipStream_t stream) {
  const float* x = (const float*)d_in[0];
  float* out = (float*)d_out;
  float* stats = (float*)d_ws;                      // 4 f32
  float* scale = stats + 4;                         // 2 f32
  double* partials = (double*)((char*)d_ws + 64);   // 1024*4 f64 = 32 KB

  stats_kernel<<<1, 256, 0, stream>>>(x, stats);
  main_kernel<<<NBLK, TPB, 0, stream>>>(x, stats, out, partials);
  scale_kernel<<<1, 64, 0, stream>>>(partials, stats, scale);
  final_kernel<<<16384 / 256, 256, 0, stream>>>(out, stats, scale);
}

// Round 5
// 60.052 us; speedup vs baseline: 4.7090x; 1.2076x over previous
//
#include <hip/hip_runtime.h>
#include <stdint.h>
#include <math.h>

#define N_PTS 8192
#define WPB   8                    // waves (rows) per block
#define TPB   (WPB * 64)           // 512 threads
#define NBLK  (N_PTS / WPB)        // 1024 blocks
#define AITER (N_PTS / 64 / 4)     // 32 uint4 iterations per lane

typedef __fp16 h2 __attribute__((ext_vector_type(2)));
typedef uint32_t u32;

// packed f16 min/max pinned to VOP3P (compiler was suspected of scalarizing)
__device__ __forceinline__ u32 pkmin(u32 a, u32 b) {
  u32 d;
  asm("v_pk_min_f16 %0, %1, %2" : "=v"(d) : "v"(a), "v"(b));
  return d;
}
__device__ __forceinline__ u32 pkmax(u32 a, u32 b) {
  u32 d;
  asm("v_pk_max_f16 %0, %1, %2" : "=v"(d) : "v"(a), "v"(b));
  return d;
}

__device__ __forceinline__ float dot2(h2 a, h2 b, float c) {
#if __has_builtin(__builtin_amdgcn_fdot2)
  return __builtin_amdgcn_fdot2(a, b, c, false);
#else
  return fmaf((float)a.x, (float)b.x, fmaf((float)a.y, (float)b.y, c));
#endif
}

// ---------------- threefry2x32 (JAX partitionable random_bits) ----------------
__device__ __forceinline__ uint32_t rotl32(uint32_t x, int r) {
  return (x << r) | (x >> (32 - r));
}

__device__ __forceinline__ uint32_t threefry_bits(uint32_t idx) {
  const uint32_t k0 = 0u, k1 = 42u;
  const uint32_t k2c = k0 ^ k1 ^ 0x1BD11BDAu;
  uint32_t x0 = 0u, x1 = idx;
  x0 += k0; x1 += k1;
  x0 += x1; x1 = rotl32(x1, 13); x1 ^= x0;
  x0 += x1; x1 = rotl32(x1, 15); x1 ^= x0;
  x0 += x1; x1 = rotl32(x1, 26); x1 ^= x0;
  x0 += x1; x1 = rotl32(x1,  6); x1 ^= x0;
  x0 += k1; x1 += k2c + 1u;
  x0 += x1; x1 = rotl32(x1, 17); x1 ^= x0;
  x0 += x1; x1 = rotl32(x1, 29); x1 ^= x0;
  x0 += x1; x1 = rotl32(x1, 16); x1 ^= x0;
  x0 += x1; x1 = rotl32(x1, 24); x1 ^= x0;
  x0 += k2c; x1 += k0 + 2u;
  x0 += x1; x1 = rotl32(x1, 13); x1 ^= x0;
  x0 += x1; x1 = rotl32(x1, 15); x1 ^= x0;
  x0 += x1; x1 = rotl32(x1, 26); x1 ^= x0;
  x0 += x1; x1 = rotl32(x1,  6); x1 ^= x0;
  x0 += k0; x1 += k1 + 3u;
  x0 += x1; x1 = rotl32(x1, 17); x1 ^= x0;
  x0 += x1; x1 = rotl32(x1, 29); x1 ^= x0;
  x0 += x1; x1 = rotl32(x1, 16); x1 ^= x0;
  x0 += x1; x1 = rotl32(x1, 24); x1 ^= x0;
  x0 += k1; x1 += k2c + 4u;
  x0 += x1; x1 = rotl32(x1, 13); x1 ^= x0;
  x0 += x1; x1 = rotl32(x1, 15); x1 ^= x0;
  x0 += x1; x1 = rotl32(x1, 26); x1 ^= x0;
  x0 += x1; x1 = rotl32(x1,  6); x1 ^= x0;
  x0 += k2c; x1 += k0 + 5u;
  return x0 ^ x1;
}

__device__ __forceinline__ float erfinv_xla(float x) {
  float w = -log1pf(-x * x);
  float p;
  if (w < 5.0f) {
    w -= 2.5f;
    p = 2.81022636e-08f;
    p = fmaf(p, w, 3.43273939e-07f);
    p = fmaf(p, w, -3.5233877e-06f);
    p = fmaf(p, w, -4.39150654e-06f);
    p = fmaf(p, w, 0.00021858087f);
    p = fmaf(p, w, -0.00125372503f);
    p = fmaf(p, w, -0.00417768164f);
    p = fmaf(p, w, 0.246640727f);
    p = fmaf(p, w, 1.50140941f);
  } else {
    w = sqrtf(w) - 3.0f;
    p = -0.000200214257f;
    p = fmaf(p, w, 0.000100950558f);
    p = fmaf(p, w, 0.00134934322f);
    p = fmaf(p, w, -0.00367342844f);
    p = fmaf(p, w, 0.00573950773f);
    p = fmaf(p, w, -0.0076224613f);
    p = fmaf(p, w, 0.00943887047f);
    p = fmaf(p, w, 1.00167406f);
    p = fmaf(p, w, 2.83297682f);
  }
  return p * x;
}

__device__ __forceinline__ float jax_noise(uint32_t idx) {
  uint32_t bits = threefry_bits(idx);
  float uf = __uint_as_float((bits >> 9) | 0x3F800000u) - 1.0f;
  const float lo_u = -0.99999994f;
  float u = fmaxf(lo_u, fmaf(uf, 2.0f, lo_u));
  return 1.4142135623730951f * erfinv_xla(u) * 0.01f;
}

// ---------------- kernel B: fused stats + sigma + drift + noised h ----------------
__global__ __launch_bounds__(TPB, 8) void main_kernel(const float* __restrict__ x,
                                                      float* __restrict__ stats,
                                                      float* __restrict__ h_out,
                                                      double* __restrict__ partials) {
  __shared__ u32 xs[N_PTS];        // packed half2 RAW points, 32 KB
  __shared__ double sred[WPB][4];  // per-wave f64 stat partials
  __shared__ float sbc[2];         // broadcast mean

  const int t = threadIdx.x;
  const int w = t >> 6;
  const int s = t & 63;
  const int row = blockIdx.x * WPB + w;

  // own point, raw f32; f16 twin bit-identical to staged copy
  const float2 xg = ((const float2*)x)[row];
  const h2 xih = __builtin_amdgcn_cvt_pkrtz(xg.x, xg.y);

  // ---- stage RAW f16 points + accumulate f64 column stats ----
  const float4* x4 = (const float4*)x;
  double s0 = 0, s1 = 0, q0 = 0, q1 = 0;
#pragma unroll
  for (int k = 0; k < N_PTS / 2 / TPB; ++k) {  // 8 iterations
    float4 v = x4[k * TPB + t];
    h2 a = __builtin_amdgcn_cvt_pkrtz(v.x, v.y);
    h2 b = __builtin_amdgcn_cvt_pkrtz(v.z, v.w);
    ((uint2*)xs)[k * TPB + t] =
        make_uint2(__builtin_bit_cast(u32, a), __builtin_bit_cast(u32, b));
    s0 += (double)v.x + (double)v.z;
    s1 += (double)v.y + (double)v.w;
    q0 += fma((double)v.x, (double)v.x, (double)v.z * (double)v.z);
    q1 += fma((double)v.y, (double)v.y, (double)v.w * (double)v.w);
  }
  // wave-level f64 reduce (identical order in every block -> deterministic)
#pragma unroll
  for (int m = 1; m < 64; m <<= 1) {
    s0 += __shfl_xor(s0, m); s1 += __shfl_xor(s1, m);
    q0 += __shfl_xor(q0, m); q1 += __shfl_xor(q1, m);
  }
  if (s == 0) { sred[w][0] = s0; sred[w][1] = s1; sred[w][2] = q0; sred[w][3] = q1; }
  __syncthreads();  // covers xs staging too
  if (t == 0) {
    double a0 = 0, a1 = 0, b0 = 0, b1 = 0;
#pragma unroll
    for (int k = 0; k < WPB; ++k) {
      a0 += sred[k][0]; a1 += sred[k][1]; b0 += sred[k][2]; b1 += sred[k][3];
    }
    double n = (double)N_PTS;
    double m0 = a0 / n, m1 = a1 / n;
    sbc[0] = (float)m0; sbc[1] = (float)m1;
    if (blockIdx.x == 0) {
      stats[0] = (float)m0;
      stats[1] = (float)m1;
      stats[2] = (float)sqrt((b0 - n * m0 * m0) / (n - 1.0));
      stats[3] = (float)sqrt((b1 - n * m1 * m1) / (n - 1.0));
    }
  }

  // ---- phase A: 4 packed cap-4 top-lists per lane (256 sub-lists per row) ----
  u32 r0[4], r1[4];
#pragma unroll
  for (int k = 0; k < 4; ++k) { r0[k] = 0x7C007C00u; r1[k] = 0x7C007C00u; }

  const uint4* xsv = (const uint4*)xs;
  __syncthreads();
#pragma unroll 4
  for (int tt = 0; tt < AITER; ++tt) {
    uint4 q = xsv[tt * 64 + s];  // 4 raw points
    h2 p0 = __builtin_bit_cast(h2, q.x), p1 = __builtin_bit_cast(h2, q.y);
    h2 p2 = __builtin_bit_cast(h2, q.z), p3 = __builtin_bit_cast(h2, q.w);
    h2 e0 = xih - p0, e1 = xih - p1, e2 = xih - p2, e3 = xih - p3;
    float d20 = dot2(e0, e0, 0.0f);
    float d21 = dot2(e1, e1, 0.0f);
    float d22 = dot2(e2, e2, 0.0f);
    float d23 = dot2(e3, e3, 0.0f);
    u32 e01 = __builtin_bit_cast(u32, __builtin_amdgcn_cvt_pkrtz(d20, d21));
    u32 e23 = __builtin_bit_cast(u32, __builtin_amdgcn_cvt_pkrtz(d22, d23));
    // branchless cap-4 sorted insert, all-packed (depth-2 dep chain)
    r0[3] = pkmin(pkmax(r0[2], e01), r0[3]);
    r0[2] = pkmin(pkmax(r0[1], e01), r0[2]);
    r0[1] = pkmin(pkmax(r0[0], e01), r0[1]);
    r0[0] = pkmin(r0[0], e01);
    r1[3] = pkmin(pkmax(r1[2], e23), r1[3]);
    r1[2] = pkmin(pkmax(r1[1], e23), r1[2]);
    r1[1] = pkmin(pkmax(r1[0], e23), r1[1]);
    r1[0] = pkmin(r1[0], e23);
  }

  // ---- exact rank-32 over 256 sorted sub-lists: binary search in u16 space ----
  u32 lo[8], hi[8];
#pragma unroll
  for (int k = 0; k < 4; ++k) {
    lo[k] = r0[k] & 0xFFFFu; hi[k] = r0[k] >> 16;
    lo[4 + k] = r1[k] & 0xFFFFu; hi[4 + k] = r1[k] >> 16;
  }
  u32 blo = 0u, bhi = 0x7C01u;
  for (int it = 0; it < 15; ++it) {
    u32 mid = (blo + bhi) >> 1;
    int c = 0;
#pragma unroll
    for (int k = 0; k < 8; ++k) {
      c += __popcll(__ballot(lo[k] < mid));
      c += __popcll(__ballot(hi[k] < mid));
    }
    bool ge = (c >= 32);
    bhi = ge ? mid : bhi;
    blo = ge ? blo : mid;
  }
  unsigned short v32 = (unsigned short)(bhi - 1u);    // 32nd-smallest d^2 (f16 bits)
  float d2k = (float)__builtin_bit_cast(__fp16, v32); // sigma^2
  float den = fmaf(2.0f, d2k, 1e-8f);
  float c1 = 1.4426950408889634f / den;
  float k22 = c1 * c1;  // w_scaled = 2^(10 - sqrt(d2*k22)); 2^10 bias cancels in drift

  // ---- phase B: weight sums (fdot2 accumulation over raw coords) ----
  const h2 one2 = __builtin_bit_cast(h2, 0x3C003C00u);
  float sw = 0.f, swx = 0.f, swy = 0.f;
#pragma unroll 4
  for (int tt = 0; tt < AITER; ++tt) {
    uint4 q = xsv[tt * 64 + s];
    h2 p0 = __builtin_bit_cast(h2, q.x), p1 = __builtin_bit_cast(h2, q.y);
    h2 p2 = __builtin_bit_cast(h2, q.z), p3 = __builtin_bit_cast(h2, q.w);
    h2 e0 = xih - p0, e1 = xih - p1, e2 = xih - p2, e3 = xih - p3;
    float d20 = dot2(e0, e0, 0.0f);
    float d21 = dot2(e1, e1, 0.0f);
    float d22 = dot2(e2, e2, 0.0f);
    float d23 = dot2(e3, e3, 0.0f);
    float w0 = __builtin_amdgcn_exp2f(10.0f - __builtin_amdgcn_sqrtf(d20 * k22));
    float w1 = __builtin_amdgcn_exp2f(10.0f - __builtin_amdgcn_sqrtf(d21 * k22));
    float w2 = __builtin_amdgcn_exp2f(10.0f - __builtin_amdgcn_sqrtf(d22 * k22));
    float w3 = __builtin_amdgcn_exp2f(10.0f - __builtin_amdgcn_sqrtf(d23 * k22));
    h2 wh01 = __builtin_amdgcn_cvt_pkrtz(w0, w1);
    h2 wh23 = __builtin_amdgcn_cvt_pkrtz(w2, w3);
    h2 xx01 = __builtin_bit_cast(h2, __builtin_amdgcn_perm(q.y, q.x, 0x05040100u));
    h2 yy01 = __builtin_bit_cast(h2, __builtin_amdgcn_perm(q.y, q.x, 0x07060302u));
    h2 xx23 = __builtin_bit_cast(h2, __builtin_amdgcn_perm(q.w, q.z, 0x05040100u));
    h2 yy23 = __builtin_bit_cast(h2, __builtin_amdgcn_perm(q.w, q.z, 0x07060302u));
    sw  = dot2(wh01, one2, sw);  sw  = dot2(wh23, one2, sw);
    swx = dot2(wh01, xx01, swx); swx = dot2(wh23, xx23, swx);
    swy = dot2(wh01, yy01, swy); swy = dot2(wh23, yy23, swy);
  }
#pragma unroll
  for (int m = 1; m < 64; m <<= 1) {
    sw  += __shfl_xor(sw,  m);
    swx += __shfl_xor(swx, m);
    swy += __shfl_xor(swy, m);
  }

  __syncthreads();           // all xs reads complete; reuse LDS front
  float* hrow = (float*)xs;  // [WPB][2]
  if (s < 2) {
    const float mean = sbc[s];
    float inv   = 1.0f / (sw + 1e-8f);  // sw scaled by 2^10 == kernel-sum scaling, cancels
    float drift = (s == 0 ? swx : swy) * inv - mean;   // centered drift
    float xcv   = (s == 0 ? xg.x : xg.y) - mean;       // centered own coord (f32 exact)
    uint32_t idx = 2u * (uint32_t)row + (uint32_t)s;
    float h = fmaf(0.5f, drift - xcv, xcv) + jax_noise(idx);  // step = D^-alpha = 0.5
    h_out[idx] = h;
    hrow[w * 2 + s] = h;
  }
  __syncthreads();
  if (t < 2) {  // deterministic per-block column partials (f64)
    double sm = 0.0, sq = 0.0;
#pragma unroll
    for (int k = 0; k < WPB; ++k) {
      double v = (double)hrow[k * 2 + t];
      sm += v; sq += v * v;
    }
    partials[blockIdx.x * 4 + t]     = sm;
    partials[blockIdx.x * 4 + 2 + t] = sq;
  }
}

// ---------------- kernel C: reduce partials -> scale = std/(cur_std+eps) ----------------
__global__ __launch_bounds__(64) void scale_kernel(const double* __restrict__ partials,
                                                   const float* __restrict__ stats,
                                                   float* __restrict__ scale) {
  __shared__ double red[64][4];
  int t = threadIdx.x;
  double a0 = 0, a1 = 0, a2 = 0, a3 = 0;
  for (int b = t; b < NBLK; b += 64) {
    a0 += partials[b * 4 + 0]; a1 += partials[b * 4 + 1];
    a2 += partials[b * 4 + 2]; a3 += partials[b * 4 + 3];
  }
  red[t][0] = a0; red[t][1] = a1; red[t][2] = a2; red[t][3] = a3;
  __syncthreads();
  if (t == 0) {
    double s0 = 0, s1 = 0, q0 = 0, q1 = 0;
    for (int k = 0; k < 64; ++k) {
      s0 += red[k][0]; s1 += red[k][1]; q0 += red[k][2]; q1 += red[k][3];
    }
    double n = (double)N_PTS;
    double m0 = s0 / n, m1 = s1 / n;
    double v0 = (q0 - n * m0 * m0) / (n - 1.0);
    double v1 = (q1 - n * m1 * m1) / (n - 1.0);
    scale[0] = stats[2] / ((float)sqrt(v0) + 1e-8f);
    scale[1] = stats[3] / ((float)sqrt(v1) + 1e-8f);
  }
}

// ---------------- kernel D: out = h*scale + mean ----------------
__global__ __launch_bounds__(256) void final_kernel(float* __restrict__ h,
                                                    const float* __restrict__ stats,
                                                    const float* __restrict__ scale) {
  int i = blockIdx.x * 256 + threadIdx.x;
  int d = i & 1;
  h[i] = fmaf(h[i], scale[d], stats[d]);
}

extern "C" void kernel_launch(void* const* d_in, const int* in_sizes, int n_in,
                              void* d_out, int out_size, void* d_ws, size_t ws_size,
                              hipStream_t stream) {
  const float* x = (const float*)d_in[0];
  float* out = (float*)d_out;
  float* stats = (float*)d_ws;                      // 4 f32
  float* scale = stats + 4;                         // 2 f32
  double* partials = (double*)((char*)d_ws + 64);   // 1024*4 f64 = 32 KB

  main_kernel<<<NBLK, TPB, 0, stream>>>(x, stats, out, partials);
  scale_kernel<<<1, 64, 0, stream>>>(partials, stats, scale);
  final_kernel<<<16384 / 256, 256, 0, stream>>>(out, stats, scale);
}

// Round 6
// 54.085 us; speedup vs baseline: 5.2285x; 1.1103x over previous
//
#include <hip/hip_runtime.h>
#include <stdint.h>
#include <math.h>

#define N_PTS 8192
#define WPB   8                    // waves (rows) per block
#define TPB   (WPB * 64)           // 512 threads
#define NBLK  (N_PTS / WPB)        // 1024 blocks
#define AITER (N_PTS / 64 / 4)     // 32 uint4 iterations per lane

typedef __fp16 h2 __attribute__((ext_vector_type(2)));
typedef uint32_t u32;

// ---- packed f16 ops pinned to VOP3P via inline asm (no scalarization possible) ----
__device__ __forceinline__ u32 pkmin(u32 a, u32 b) {
  u32 d; asm("v_pk_min_f16 %0, %1, %2" : "=v"(d) : "v"(a), "v"(b)); return d;
}
__device__ __forceinline__ u32 pkmax(u32 a, u32 b) {
  u32 d; asm("v_pk_max_f16 %0, %1, %2" : "=v"(d) : "v"(a), "v"(b)); return d;
}
__device__ __forceinline__ u32 pksub(u32 a, u32 b) {  // a - b, both halves
  u32 d;
  asm("v_pk_add_f16 %0, %1, %2 neg_lo:[0,1] neg_hi:[0,1]" : "=v"(d) : "v"(a), "v"(b));
  return d;
}
__device__ __forceinline__ float dot2u(u32 a, u32 b, float c) {  // a.x*b.x + a.y*b.y + c
  return __builtin_amdgcn_fdot2(__builtin_bit_cast(h2, a), __builtin_bit_cast(h2, b), c, false);
}
__device__ __forceinline__ u32 cvtpk(float a, float b) {  // pack (a,b) -> f16x2 (RTZ)
  return __builtin_bit_cast(u32, __builtin_amdgcn_cvt_pkrtz(a, b));
}

// ---------------- threefry2x32 (JAX partitionable random_bits) ----------------
__device__ __forceinline__ uint32_t rotl32(uint32_t x, int r) {
  return (x << r) | (x >> (32 - r));
}

__device__ __forceinline__ uint32_t threefry_bits(uint32_t idx) {
  const uint32_t k0 = 0u, k1 = 42u;
  const uint32_t k2c = k0 ^ k1 ^ 0x1BD11BDAu;
  uint32_t x0 = 0u, x1 = idx;
  x0 += k0; x1 += k1;
  x0 += x1; x1 = rotl32(x1, 13); x1 ^= x0;
  x0 += x1; x1 = rotl32(x1, 15); x1 ^= x0;
  x0 += x1; x1 = rotl32(x1, 26); x1 ^= x0;
  x0 += x1; x1 = rotl32(x1,  6); x1 ^= x0;
  x0 += k1; x1 += k2c + 1u;
  x0 += x1; x1 = rotl32(x1, 17); x1 ^= x0;
  x0 += x1; x1 = rotl32(x1, 29); x1 ^= x0;
  x0 += x1; x1 = rotl32(x1, 16); x1 ^= x0;
  x0 += x1; x1 = rotl32(x1, 24); x1 ^= x0;
  x0 += k2c; x1 += k0 + 2u;
  x0 += x1; x1 = rotl32(x1, 13); x1 ^= x0;
  x0 += x1; x1 = rotl32(x1, 15); x1 ^= x0;
  x0 += x1; x1 = rotl32(x1, 26); x1 ^= x0;
  x0 += x1; x1 = rotl32(x1,  6); x1 ^= x0;
  x0 += k0; x1 += k1 + 3u;
  x0 += x1; x1 = rotl32(x1, 17); x1 ^= x0;
  x0 += x1; x1 = rotl32(x1, 29); x1 ^= x0;
  x0 += x1; x1 = rotl32(x1, 16); x1 ^= x0;
  x0 += x1; x1 = rotl32(x1, 24); x1 ^= x0;
  x0 += k1; x1 += k2c + 4u;
  x0 += x1; x1 = rotl32(x1, 13); x1 ^= x0;
  x0 += x1; x1 = rotl32(x1, 15); x1 ^= x0;
  x0 += x1; x1 = rotl32(x1, 26); x1 ^= x0;
  x0 += x1; x1 = rotl32(x1,  6); x1 ^= x0;
  x0 += k2c; x1 += k0 + 5u;
  return x0 ^ x1;
}

__device__ __forceinline__ float erfinv_xla(float x) {
  float w = -log1pf(-x * x);
  float p;
  if (w < 5.0f) {
    w -= 2.5f;
    p = 2.81022636e-08f;
    p = fmaf(p, w, 3.43273939e-07f);
    p = fmaf(p, w, -3.5233877e-06f);
    p = fmaf(p, w, -4.39150654e-06f);
    p = fmaf(p, w, 0.00021858087f);
    p = fmaf(p, w, -0.00125372503f);
    p = fmaf(p, w, -0.00417768164f);
    p = fmaf(p, w, 0.246640727f);
    p = fmaf(p, w, 1.50140941f);
  } else {
    w = sqrtf(w) - 3.0f;
    p = -0.000200214257f;
    p = fmaf(p, w, 0.000100950558f);
    p = fmaf(p, w, 0.00134934322f);
    p = fmaf(p, w, -0.00367342844f);
    p = fmaf(p, w, 0.00573950773f);
    p = fmaf(p, w, -0.0076224613f);
    p = fmaf(p, w, 0.00943887047f);
    p = fmaf(p, w, 1.00167406f);
    p = fmaf(p, w, 2.83297682f);
  }
  return p * x;
}

__device__ __forceinline__ float jax_noise(uint32_t idx) {
  uint32_t bits = threefry_bits(idx);
  float uf = __uint_as_float((bits >> 9) | 0x3F800000u) - 1.0f;
  const float lo_u = -0.99999994f;
  float u = fmaxf(lo_u, fmaf(uf, 2.0f, lo_u));
  return 1.4142135623730951f * erfinv_xla(u) * 0.01f;
}

// ---------------- kernel B: fused stats + sigma + drift + noised h ----------------
__global__ __launch_bounds__(TPB, 8) void main_kernel(const float* __restrict__ x,
                                                      float* __restrict__ stats,
                                                      float* __restrict__ h_out,
                                                      double* __restrict__ partials) {
  __shared__ u32 xs[N_PTS];        // packed half2 RAW points, 32 KB
  __shared__ double sred[WPB][4];  // per-wave f64 stat partials
  __shared__ float sbc[2];         // broadcast mean

  const int t = threadIdx.x;
  const int w = t >> 6;
  const int s = t & 63;
  const int row = blockIdx.x * WPB + w;

  // own point, raw f32; f16 twin bit-identical to staged copy
  const float2 xg = ((const float2*)x)[row];
  const u32 xihu = cvtpk(xg.x, xg.y);

  // ---- stage RAW f16 points + accumulate f64 column stats ----
  const float4* x4 = (const float4*)x;
  double s0 = 0, s1 = 0, q0 = 0, q1 = 0;
#pragma unroll
  for (int k = 0; k < N_PTS / 2 / TPB; ++k) {  // 8 iterations
    float4 v = x4[k * TPB + t];
    ((uint2*)xs)[k * TPB + t] = make_uint2(cvtpk(v.x, v.y), cvtpk(v.z, v.w));
    s0 += (double)v.x + (double)v.z;
    s1 += (double)v.y + (double)v.w;
    q0 += fma((double)v.x, (double)v.x, (double)v.z * (double)v.z);
    q1 += fma((double)v.y, (double)v.y, (double)v.w * (double)v.w);
  }
  // wave-level f64 reduce (identical order in every block -> deterministic)
#pragma unroll
  for (int m = 1; m < 64; m <<= 1) {
    s0 += __shfl_xor(s0, m); s1 += __shfl_xor(s1, m);
    q0 += __shfl_xor(q0, m); q1 += __shfl_xor(q1, m);
  }
  if (s == 0) { sred[w][0] = s0; sred[w][1] = s1; sred[w][2] = q0; sred[w][3] = q1; }
  __syncthreads();  // covers xs staging too
  if (t == 0) {
    double a0 = 0, a1 = 0, b0 = 0, b1 = 0;
#pragma unroll
    for (int k = 0; k < WPB; ++k) {
      a0 += sred[k][0]; a1 += sred[k][1]; b0 += sred[k][2]; b1 += sred[k][3];
    }
    double n = (double)N_PTS;
    double m0 = a0 / n, m1 = a1 / n;
    sbc[0] = (float)m0; sbc[1] = (float)m1;
    if (blockIdx.x == 0) {
      stats[0] = (float)m0;
      stats[1] = (float)m1;
      stats[2] = (float)sqrt((b0 - n * m0 * m0) / (n - 1.0));
      stats[3] = (float)sqrt((b1 - n * m1 * m1) / (n - 1.0));
    }
  }

  // ---- phase A: 4 packed cap-4 top-lists per lane (256 sub-lists per row) ----
  u32 r0[4], r1[4];
#pragma unroll
  for (int k = 0; k < 4; ++k) { r0[k] = 0x7C007C00u; r1[k] = 0x7C007C00u; }

  const uint4* xsv = (const uint4*)xs;
  __syncthreads();
#pragma unroll 8
  for (int tt = 0; tt < AITER; ++tt) {
    uint4 q = xsv[tt * 64 + s];  // 4 raw points
    u32 e0 = pksub(xihu, q.x);
    u32 e1 = pksub(xihu, q.y);
    u32 e2 = pksub(xihu, q.z);
    u32 e3 = pksub(xihu, q.w);
    u32 e01 = cvtpk(dot2u(e0, e0, 0.0f), dot2u(e1, e1, 0.0f));
    u32 e23 = cvtpk(dot2u(e2, e2, 0.0f), dot2u(e3, e3, 0.0f));
    // branchless cap-4 sorted insert, all-packed (depth-2 dep chain)
    r0[3] = pkmin(pkmax(r0[2], e01), r0[3]);
    r0[2] = pkmin(pkmax(r0[1], e01), r0[2]);
    r0[1] = pkmin(pkmax(r0[0], e01), r0[1]);
    r0[0] = pkmin(r0[0], e01);
    r1[3] = pkmin(pkmax(r1[2], e23), r1[3]);
    r1[2] = pkmin(pkmax(r1[1], e23), r1[2]);
    r1[1] = pkmin(pkmax(r1[0], e23), r1[1]);
    r1[0] = pkmin(r1[0], e23);
  }

  // ---- exact rank-32 over 256 sorted sub-lists: binary search in u16 space ----
  u32 lo[8], hi[8];
#pragma unroll
  for (int k = 0; k < 4; ++k) {
    lo[k] = r0[k] & 0xFFFFu; hi[k] = r0[k] >> 16;
    lo[4 + k] = r1[k] & 0xFFFFu; hi[4 + k] = r1[k] >> 16;
  }
  u32 blo = 0u, bhi = 0x7C01u;
  for (int it = 0; it < 15; ++it) {
    u32 mid = (blo + bhi) >> 1;
    int c = 0;
#pragma unroll
    for (int k = 0; k < 8; ++k) {
      c += __popcll(__ballot(lo[k] < mid));
      c += __popcll(__ballot(hi[k] < mid));
    }
    bool ge = (c >= 32);
    bhi = ge ? mid : bhi;
    blo = ge ? blo : mid;
  }
  unsigned short v32 = (unsigned short)(bhi - 1u);    // 32nd-smallest d^2 (f16 bits)
  float d2k = (float)__builtin_bit_cast(__fp16, v32); // sigma^2
  float den = fmaf(2.0f, d2k, 1e-8f);
  float nc1 = -1.4426950408889634f / den;  // w_scaled = 2^(10 + nc1*d); 2^10 bias cancels

  // ---- phase B: weight sums (fdot2 accumulation over raw coords) ----
  const u32 one2 = 0x3C003C00u;  // (1.0h, 1.0h)
  float sw = 0.f, swx = 0.f, swy = 0.f;
#pragma unroll 4
  for (int tt = 0; tt < AITER; ++tt) {
    uint4 q = xsv[tt * 64 + s];
    u32 e0 = pksub(xihu, q.x);
    u32 e1 = pksub(xihu, q.y);
    u32 e2 = pksub(xihu, q.z);
    u32 e3 = pksub(xihu, q.w);
    float d0 = __builtin_amdgcn_sqrtf(dot2u(e0, e0, 0.0f));
    float d1 = __builtin_amdgcn_sqrtf(dot2u(e1, e1, 0.0f));
    float d2 = __builtin_amdgcn_sqrtf(dot2u(e2, e2, 0.0f));
    float d3 = __builtin_amdgcn_sqrtf(dot2u(e3, e3, 0.0f));
    float w0 = __builtin_amdgcn_exp2f(fmaf(nc1, d0, 10.0f));
    float w1 = __builtin_amdgcn_exp2f(fmaf(nc1, d1, 10.0f));
    float w2 = __builtin_amdgcn_exp2f(fmaf(nc1, d2, 10.0f));
    float w3 = __builtin_amdgcn_exp2f(fmaf(nc1, d3, 10.0f));
    u32 wh01 = cvtpk(w0, w1);
    u32 wh23 = cvtpk(w2, w3);
    u32 xx01 = __builtin_amdgcn_perm(q.y, q.x, 0x05040100u);
    u32 yy01 = __builtin_amdgcn_perm(q.y, q.x, 0x07060302u);
    u32 xx23 = __builtin_amdgcn_perm(q.w, q.z, 0x05040100u);
    u32 yy23 = __builtin_amdgcn_perm(q.w, q.z, 0x07060302u);
    sw  = dot2u(wh01, one2, sw);  sw  = dot2u(wh23, one2, sw);
    swx = dot2u(wh01, xx01, swx); swx = dot2u(wh23, xx23, swx);
    swy = dot2u(wh01, yy01, swy); swy = dot2u(wh23, yy23, swy);
  }
#pragma unroll
  for (int m = 1; m < 64; m <<= 1) {
    sw  += __shfl_xor(sw,  m);
    swx += __shfl_xor(swx, m);
    swy += __shfl_xor(swy, m);
  }

  __syncthreads();           // all xs reads complete; reuse LDS front
  float* hrow = (float*)xs;  // [WPB][2]
  if (s < 2) {
    const float mean = sbc[s];
    float inv   = 1.0f / (sw + 1e-8f);  // 2^10 scaling cancels in drift
    float drift = (s == 0 ? swx : swy) * inv - mean;   // centered drift
    float xcv   = (s == 0 ? xg.x : xg.y) - mean;       // centered own coord (f32 exact)
    uint32_t idx = 2u * (uint32_t)row + (uint32_t)s;
    float h = fmaf(0.5f, drift - xcv, xcv) + jax_noise(idx);  // step = D^-alpha = 0.5
    h_out[idx] = h;
    hrow[w * 2 + s] = h;
  }
  __syncthreads();
  if (t < 2) {  // deterministic per-block column partials (f64)
    double sm = 0.0, sq = 0.0;
#pragma unroll
    for (int k = 0; k < WPB; ++k) {
      double v = (double)hrow[k * 2 + t];
      sm += v; sq += v * v;
    }
    partials[blockIdx.x * 4 + t]     = sm;
    partials[blockIdx.x * 4 + 2 + t] = sq;
  }
}

// ------- kernel C: every block reduces partials (deterministic) + scales its slice -------
__global__ __launch_bounds__(256) void scalefinal_kernel(const double* __restrict__ partials,
                                                         const float* __restrict__ stats,
                                                         float* __restrict__ h) {
  __shared__ double red[256][4];
  __shared__ float sc[2];
  const int t = threadIdx.x;
  double a0 = 0, a1 = 0, a2 = 0, a3 = 0;
#pragma unroll
  for (int kb = 0; kb < NBLK / 256; ++kb) {  // 4 iterations
    int b = kb * 256 + t;
    a0 += partials[b * 4 + 0]; a1 += partials[b * 4 + 1];
    a2 += partials[b * 4 + 2]; a3 += partials[b * 4 + 3];
  }
  red[t][0] = a0; red[t][1] = a1; red[t][2] = a2; red[t][3] = a3;
  __syncthreads();
  for (int st = 128; st > 0; st >>= 1) {
    if (t < st) {
      red[t][0] += red[t + st][0]; red[t][1] += red[t + st][1];
      red[t][2] += red[t + st][2]; red[t][3] += red[t + st][3];
    }
    __syncthreads();
  }
  if (t < 2) {
    double n = (double)N_PTS;
    double m = red[0][t] / n;
    double v = (red[0][2 + t] - n * m * m) / (n - 1.0);
    sc[t] = stats[2 + t] / ((float)sqrt(v) + 1e-8f);
  }
  __syncthreads();
  int i = blockIdx.x * 256 + t;
  int d = i & 1;
  h[i] = fmaf(h[i], sc[d], stats[d]);
}

extern "C" void kernel_launch(void* const* d_in, const int* in_sizes, int n_in,
                              void* d_out, int out_size, void* d_ws, size_t ws_size,
                              hipStream_t stream) {
  const float* x = (const float*)d_in[0];
  float* out = (float*)d_out;
  float* stats = (float*)d_ws;                      // 4 f32
  double* partials = (double*)((char*)d_ws + 64);   // 1024*4 f64 = 32 KB

  main_kernel<<<NBLK, TPB, 0, stream>>>(x, stats, out, partials);
  scalefinal_kernel<<<16384 / 256, 256, 0, stream>>>(partials, stats, out);
}